// Round 17
// baseline (274.646 us; speedup 1.0000x reference)
//
#include <hip/hip_runtime.h>

// ---------------------------------------------------------------------------
// Round-16 pipeline with spmm column-split + XCD-pinned gather:
//  spmm: each block handles 4 nodes x ONE 32-dim column half; column half is
//  chosen by (blockIdx>>2)&1 so that (if dispatch round-robins blocks over the
//  8 XCDs) each XCD only ever touches 3.2 MB of fb16 -> fits its 4 MB L2.
//  Correct for ANY dispatch mapping (pure blockIdx bijection); fast if %8.
// ---------------------------------------------------------------------------

#define TILE 8192

typedef __attribute__((ext_vector_type(8))) unsigned short us8;

__device__ __forceinline__ float b2f(unsigned short h) {
    return __uint_as_float(((unsigned)h) << 16);
}
__device__ __forceinline__ unsigned short f2b(float f) {
    const unsigned u = __float_as_uint(f);
    return (unsigned short)((u + 0x7FFFu + ((u >> 16) & 1u)) >> 16);
}

__device__ __forceinline__ unsigned ford_enc(float v) {
    unsigned b = __float_as_uint(v);
    return (b & 0x80000000u) ? ~b : (b | 0x80000000u);
}
__device__ __forceinline__ float ford_dec(unsigned k) {
    return __uint_as_float((k & 0x80000000u) ? (k ^ 0x80000000u) : ~k);
}

__global__ __launch_bounds__(512) void agnn_kernel(
    const float* __restrict__ cl_h, const float* __restrict__ cl_w,
    const int* __restrict__ cl_src, const int* __restrict__ cl_dst,
    const float* __restrict__ W_e,
    const float* __restrict__ pb1, const float* __restrict__ pe1,
    const float* __restrict__ pb2, const float* __restrict__ pe2,
    float* __restrict__ hW, int* __restrict__ bcnt, int ECL)
{
    __shared__ float w_s[1024];
    __shared__ int   src_s[1024];
    __shared__ int   dst_s[1024];
    __shared__ float h[32][16];
    __shared__ float nh[32][16];
    __shared__ float p[1024];
    __shared__ float red[32][16];
    __shared__ float acc16[32][16][16];
    __shared__ unsigned mI[32];
    __shared__ float m[32], ssum[32], nrm[32];
    const int tid = threadIdx.x;
    const int seg = tid >> 4, j = tid & 15;

    if (tid < 256) bcnt[tid] = 0;

    for (int e = tid; e < ECL; e += 512) {
        w_s[e] = cl_w[e]; src_s[e] = cl_src[e]; dst_s[e] = cl_dst[e];
    }
    h[tid >> 4][tid & 15] = cl_h[tid];
    __syncthreads();

    for (int layer = 0; layer < 2; ++layer) {
        const float beta = layer ? *pb2 : *pb1;
        const float eps  = layer ? *pe2 : *pe1;

        if (tid < 32) mI[tid] = ford_enc(-3.4e38f);
        __syncthreads();
        for (int e = tid; e < ECL; e += 512)
            atomicMax(&mI[src_s[e]], ford_enc(beta * w_s[e]));
        __syncthreads();
        if (tid < 32) m[tid] = ford_dec(mI[tid]);
        __syncthreads();

        for (int e = tid; e < ECL; e += 512)
            p[e] = __expf(beta * w_s[e] - m[src_s[e]]);
        __syncthreads();

        {
            float s = 0.f;
            #pragma unroll 4
            for (int e = j; e < ECL; e += 16)
                s += (src_s[e] == seg) ? p[e] : 0.f;
            red[seg][j] = s;
        }
        __syncthreads();
        if (tid < 32) {
            float s = 0.f;
            #pragma unroll
            for (int k = 0; k < 16; ++k) s += red[tid][k];
            ssum[tid] = s;
            float q = 0.f;
            #pragma unroll
            for (int f = 0; f < 16; ++f) { float v = h[tid][f]; q += v * v; }
            nrm[tid] = fmaxf(sqrtf(q), 1e-12f);
        }
        __syncthreads();
        for (int e = tid; e < ECL; e += 512)
            p[e] = p[e] / ssum[src_s[e]];
        nh[tid >> 4][tid & 15] = h[tid >> 4][tid & 15] / nrm[tid >> 4];
        __syncthreads();

        {
            float facc[16];
            #pragma unroll
            for (int f = 0; f < 16; ++f) facc[f] = 0.f;
            #pragma unroll 4
            for (int e = j; e < ECL; e += 16) {
                if (dst_s[e] == seg) {
                    const float pe = p[e];
                    const float4* nhrow = reinterpret_cast<const float4*>(&nh[src_s[e]][0]);
                    const float4 a0 = nhrow[0], a1 = nhrow[1], a2 = nhrow[2], a3 = nhrow[3];
                    facc[0] += pe * a0.x; facc[1] += pe * a0.y; facc[2] += pe * a0.z; facc[3] += pe * a0.w;
                    facc[4] += pe * a1.x; facc[5] += pe * a1.y; facc[6] += pe * a1.z; facc[7] += pe * a1.w;
                    facc[8] += pe * a2.x; facc[9] += pe * a2.y; facc[10] += pe * a2.z; facc[11] += pe * a2.w;
                    facc[12] += pe * a3.x; facc[13] += pe * a3.y; facc[14] += pe * a3.z; facc[15] += pe * a3.w;
                }
            }
            #pragma unroll
            for (int f = 0; f < 16; ++f) acc16[seg][j][f] = facc[f];
        }
        __syncthreads();
        {
            const int t = tid >> 4, f = tid & 15;
            float a = 0.f;
            #pragma unroll
            for (int k = 0; k < 16; ++k) a += acc16[t][k][f];
            float v = (1.f + eps) * h[t][f] + a;
            h[t][f] = fmaxf(v, 0.f);
        }
        __syncthreads();
    }

    for (int o = tid; o < 2048; o += 512) {
        const int t = o >> 6, d = o & 63;
        float s = 0.f;
        #pragma unroll
        for (int f = 0; f < 16; ++f) s += h[t][f] * W_e[f * 64 + d];
        hW[o] = s;
    }
}

__global__ __launch_bounds__(256) void tobf16_kernel(
    const float* __restrict__ x, unsigned short* __restrict__ y, int total8)
{
    const int i = blockIdx.x * 256 + threadIdx.x;
    if (i >= total8) return;
    const int base = i * 8;
    const float4 a = *reinterpret_cast<const float4*>(&x[base]);
    const float4 b = *reinterpret_cast<const float4*>(&x[base + 4]);
    us8 o;
    o[0] = f2b(a.x); o[1] = f2b(a.y); o[2] = f2b(a.z); o[3] = f2b(a.w);
    o[4] = f2b(b.x); o[5] = f2b(b.y); o[6] = f2b(b.z); o[7] = f2b(b.w);
    *reinterpret_cast<us8*>(&y[base]) = o;
}

__global__ __launch_bounds__(256) void bucket_count(
    const int* __restrict__ dst, int* __restrict__ bcnt, int E)
{
    __shared__ int lh[256];
    const int tid = threadIdx.x;
    lh[tid] = 0;
    __syncthreads();
    const int base = blockIdx.x * TILE;
    #pragma unroll
    for (int it = 0; it < 8; ++it) {
        const int i = base + (it * 256 + tid) * 4;
        if (i + 3 < E) {
            const int4 d = *reinterpret_cast<const int4*>(&dst[i]);
            atomicAdd(&lh[d.x >> 8], 1); atomicAdd(&lh[d.y >> 8], 1);
            atomicAdd(&lh[d.z >> 8], 1); atomicAdd(&lh[d.w >> 8], 1);
        } else {
            for (int k = i; k < E && k < i + 4; ++k) atomicAdd(&lh[dst[k] >> 8], 1);
        }
    }
    __syncthreads();
    if (lh[tid]) atomicAdd(&bcnt[tid], lh[tid]);
}

__global__ __launch_bounds__(256) void bucket_scan(
    const int* __restrict__ bcnt, int* __restrict__ bbase, int* __restrict__ bcur)
{
    __shared__ int ws[4];
    const int tid = threadIdx.x, lane = tid & 63, wv = tid >> 6;
    const int v = bcnt[tid];
    int x = v;
    #pragma unroll
    for (int s = 1; s < 64; s <<= 1) { const int t = __shfl_up(x, s, 64); if (lane >= s) x += t; }
    if (lane == 63) ws[wv] = x;
    __syncthreads();
    if (tid == 0) { int a = ws[0]; ws[0] = 0; for (int k = 1; k < 4; ++k) { const int b = ws[k]; ws[k] = a; a += b; } }
    __syncthreads();
    const int excl = ws[wv] + x - v;
    bbase[tid] = excl; bcur[tid] = excl;
    if (tid == 255) bbase[256] = excl + v;
}

__global__ __launch_bounds__(256) void bucket_scatter(
    const int* __restrict__ src, const int* __restrict__ dst, const int* __restrict__ et,
    int* __restrict__ bcur, unsigned* __restrict__ etmp, int E)
{
    __shared__ int lh[256], lofs[256], lcur[256], gbase[256];
    __shared__ int ws[4];
    __shared__ unsigned stage[TILE];
    __shared__ unsigned char sbk[TILE];
    const int tid = threadIdx.x, lane = tid & 63, wv = tid >> 6;
    lh[tid] = 0;
    __syncthreads();
    const int base = blockIdx.x * TILE;
    #pragma unroll
    for (int it = 0; it < 8; ++it) {
        const int i = base + (it * 256 + tid) * 4;
        if (i + 3 < E) {
            const int4 d = *reinterpret_cast<const int4*>(&dst[i]);
            atomicAdd(&lh[d.x >> 8], 1); atomicAdd(&lh[d.y >> 8], 1);
            atomicAdd(&lh[d.z >> 8], 1); atomicAdd(&lh[d.w >> 8], 1);
        } else {
            for (int k = i; k < E && k < i + 4; ++k) atomicAdd(&lh[dst[k] >> 8], 1);
        }
    }
    __syncthreads();
    {
        const int v = lh[tid];
        int x = v;
        #pragma unroll
        for (int s = 1; s < 64; s <<= 1) { const int t = __shfl_up(x, s, 64); if (lane >= s) x += t; }
        if (lane == 63) ws[wv] = x;
        __syncthreads();
        if (tid == 0) { int a = ws[0]; ws[0] = 0; for (int k = 1; k < 4; ++k) { const int b = ws[k]; ws[k] = a; a += b; } }
        __syncthreads();
        const int excl = ws[wv] + x - v;
        lofs[tid] = excl; lcur[tid] = excl;
        if (v) gbase[tid] = atomicAdd(&bcur[tid], v);
    }
    __syncthreads();
    #pragma unroll
    for (int it = 0; it < 8; ++it) {
        const int i = base + (it * 256 + tid) * 4;
        if (i + 3 < E) {
            const int4 d  = *reinterpret_cast<const int4*>(&dst[i]);
            const int4 s4 = *reinterpret_cast<const int4*>(&src[i]);
            const int4 t4 = *reinterpret_cast<const int4*>(&et[i]);
            int b, r;
            b = d.x >> 8; r = atomicAdd(&lcur[b], 1);
            stage[r] = (unsigned)s4.x | ((unsigned)(d.x & 255) << 16) | ((unsigned)t4.x << 24); sbk[r] = (unsigned char)b;
            b = d.y >> 8; r = atomicAdd(&lcur[b], 1);
            stage[r] = (unsigned)s4.y | ((unsigned)(d.y & 255) << 16) | ((unsigned)t4.y << 24); sbk[r] = (unsigned char)b;
            b = d.z >> 8; r = atomicAdd(&lcur[b], 1);
            stage[r] = (unsigned)s4.z | ((unsigned)(d.z & 255) << 16) | ((unsigned)t4.z << 24); sbk[r] = (unsigned char)b;
            b = d.w >> 8; r = atomicAdd(&lcur[b], 1);
            stage[r] = (unsigned)s4.w | ((unsigned)(d.w & 255) << 16) | ((unsigned)t4.w << 24); sbk[r] = (unsigned char)b;
        } else {
            for (int k = i; k < E && k < i + 4; ++k) {
                const int b = dst[k] >> 8;
                const int r = atomicAdd(&lcur[b], 1);
                stage[r] = (unsigned)src[k] | ((unsigned)(dst[k] & 255) << 16) | ((unsigned)et[k] << 24);
                sbk[r] = (unsigned char)b;
            }
        }
    }
    __syncthreads();
    const int tot = lofs[255] + lh[255];
    for (int i = tid; i < tot; i += 256) {
        const int b = sbk[i];
        etmp[gbase[b] + (i - lofs[b])] = stage[i];
    }
}

__global__ __launch_bounds__(256) void csr_kernel(
    const unsigned* __restrict__ etmp, const int* __restrict__ bbase,
    int* __restrict__ off, unsigned* __restrict__ ssrc, int N, int NB)
{
    __shared__ int lh[256], lofs[256], lcur[256];
    __shared__ int ws[4];
    const int tid = threadIdx.x, lane = tid & 63, wv = tid >> 6;
    const int b = blockIdx.x;
    const int s = bbase[b], e = bbase[b + 1];
    lh[tid] = 0;
    __syncthreads();
    for (int i = s + tid; i < e; i += 256)
        atomicAdd(&lh[(etmp[i] >> 16) & 255], 1);
    __syncthreads();
    {
        const int v = lh[tid];
        int x = v;
        #pragma unroll
        for (int ss = 1; ss < 64; ss <<= 1) { const int t = __shfl_up(x, ss, 64); if (lane >= ss) x += t; }
        if (lane == 63) ws[wv] = x;
        __syncthreads();
        if (tid == 0) { int a = ws[0]; ws[0] = 0; for (int k = 1; k < 4; ++k) { const int c = ws[k]; ws[k] = a; a += c; } }
        __syncthreads();
        const int excl = ws[wv] + x - v;
        lofs[tid] = excl; lcur[tid] = excl;
    }
    __syncthreads();
    const int n0 = b << 8;
    if (n0 + tid < N) off[n0 + tid] = s + lofs[tid];
    if (b == NB - 1 && tid == 0) off[N] = e;
    for (int i = s + tid; i < e; i += 256) {
        const unsigned pp = etmp[i];
        const int dl = (pp >> 16) & 255;
        const int r = atomicAdd(&lcur[dl], 1);
        ssrc[s + r] = pp;
    }
}

// Column-split gather: block -> (node-group, column-half) with column-half
// keyed to (blockIdx>>2)&1 so round-robin XCD dispatch pins each 3.2 MB
// half-table to one XCD group's L2s. Wave = node: 4 edge-slots x 16 dim-lanes.
__global__ __launch_bounds__(256) void spmm_kernel(
    const unsigned short* __restrict__ fb, const float* __restrict__ hW,
    const int* __restrict__ off, const unsigned* __restrict__ ssrc,
    float* __restrict__ aggF, int N)
{
    __shared__ float hWl[2048];
    for (int i = threadIdx.x; i < 2048; i += 256) hWl[i] = hW[i];
    __syncthreads();
    const int bid = blockIdx.x;
    const int cg  = (bid >> 2) & 1;                 // column half (XCD-keyed)
    const int ng  = (bid >> 3) * 4 + (bid & 3);     // node group
    const int n = ng * 4 + (threadIdx.x >> 6);
    if (n >= N) return;
    const int lane = threadIdx.x & 63;
    const int slot = lane >> 4;                     // 4 edge slots
    const int dbase = cg * 32 + 2 * (lane & 15);    // 2 dims per lane
    const int beg = off[n], end = off[n + 1];
    float a0 = 0.f, a1 = 0.f;
    int i = beg;
    for (; i + 15 < end; i += 16) {                 // 16 edges in flight / wave
        unsigned pp[4];
        #pragma unroll
        for (int j = 0; j < 4; ++j) pp[j] = ssrc[i + 4 * j + slot];
        unsigned u[4];
        #pragma unroll
        for (int j = 0; j < 4; ++j)
            u[j] = *reinterpret_cast<const unsigned*>(
                &fb[(size_t)(pp[j] & 0xFFFFu) * 64 + dbase]);
        #pragma unroll
        for (int j = 0; j < 4; ++j) {
            const float2 hw = *reinterpret_cast<const float2*>(
                &hWl[(pp[j] >> 24) * 64 + dbase]);
            a0 += b2f((unsigned short)(u[j] & 0xFFFFu)) - hw.x;
            a1 += b2f((unsigned short)(u[j] >> 16)) - hw.y;
        }
    }
    for (int e = i + slot; e < end; e += 4) {
        const unsigned pp = ssrc[e];
        const unsigned u = *reinterpret_cast<const unsigned*>(
            &fb[(size_t)(pp & 0xFFFFu) * 64 + dbase]);
        const float2 hw = *reinterpret_cast<const float2*>(
            &hWl[(pp >> 24) * 64 + dbase]);
        a0 += b2f((unsigned short)(u & 0xFFFFu)) - hw.x;
        a1 += b2f((unsigned short)(u >> 16)) - hw.y;
    }
    a0 += __shfl_xor(a0, 16); a0 += __shfl_xor(a0, 32);
    a1 += __shfl_xor(a1, 16); a1 += __shfl_xor(a1, 32);
    if (slot == 0)
        *reinterpret_cast<float2*>(&aggF[(size_t)n * 64 + dbase]) =
            make_float2(a0, a1);
}

// Register-tiled GEMM: thread (ng=tid&15, og=tid>>4) computes 4 nodes x 4 outs.
__global__ __launch_bounds__(256) void gconv_kernel(
    const float* __restrict__ Xf, const float* __restrict__ Af,
    const float* __restrict__ W1, const float* __restrict__ W2,
    float* __restrict__ x1f, unsigned short* __restrict__ out16,
    float* __restrict__ outf, int N, int final_mode,
    const float* __restrict__ Wp, const float* __restrict__ bp)
{
    __shared__ float4 fav[64 * 32];   // A/X, 32 KB, chunk ^= (row>>2)&7 swizzle
    __shared__ float4 Wl[128 * 16];   // W rows, 32 KB
    const int tid = threadIdx.x;
    const int ng = tid & 15, og = tid >> 4;
    const int n0 = blockIdx.x * 64;
    const int nb = ng * 4;

    #pragma unroll
    for (int q = 0; q < 8; ++q) {
        const int idx = q * 256 + tid;     // 0..2047
        Wl[idx] = (idx < 1024)
            ? reinterpret_cast<const float4*>(W1)[idx]
            : reinterpret_cast<const float4*>(W2)[idx - 1024];
    }
    #pragma unroll
    for (int q = 0; q < 8; ++q) {
        const int cch = q * 256 + tid;     // 0..2047
        const int row = cch >> 5, p = cch & 31;
        const int rn = n0 + row;
        float4 v = make_float4(0.f, 0.f, 0.f, 0.f);
        if (rn < N)
            v = (p < 16) ? reinterpret_cast<const float4*>(Xf)[(size_t)rn * 16 + p]
                         : reinterpret_cast<const float4*>(Af)[(size_t)rn * 16 + (p - 16)];
        fav[row * 32 + (p ^ ((row >> 2) & 7))] = v;
    }
    __syncthreads();

    float acc[4][4];
    #pragma unroll
    for (int i = 0; i < 4; ++i)
        #pragma unroll
        for (int j = 0; j < 4; ++j) acc[i][j] = 0.f;

    const int swz = ng & 7;
    #pragma unroll 2
    for (int kc = 0; kc < 32; ++kc) {
        const int pc = kc ^ swz;
        const float4 a0 = fav[(nb + 0) * 32 + pc];
        const float4 a1 = fav[(nb + 1) * 32 + pc];
        const float4 a2 = fav[(nb + 2) * 32 + pc];
        const float4 a3 = fav[(nb + 3) * 32 + pc];
        const float4 w0 = Wl[(kc * 4 + 0) * 16 + og];
        const float4 w1 = Wl[(kc * 4 + 1) * 16 + og];
        const float4 w2 = Wl[(kc * 4 + 2) * 16 + og];
        const float4 w3 = Wl[(kc * 4 + 3) * 16 + og];
        #pragma unroll
        for (int i = 0; i < 4; ++i) {
            const float4 a = (i == 0) ? a0 : (i == 1) ? a1 : (i == 2) ? a2 : a3;
            acc[i][0] += a.x * w0.x + a.y * w1.x + a.z * w2.x + a.w * w3.x;
            acc[i][1] += a.x * w0.y + a.y * w1.y + a.z * w2.y + a.w * w3.y;
            acc[i][2] += a.x * w0.z + a.y * w1.z + a.z * w2.z + a.w * w3.z;
            acc[i][3] += a.x * w0.w + a.y * w1.w + a.z * w2.w + a.w * w3.w;
        }
    }

    #pragma unroll
    for (int i = 0; i < 4; ++i)
        #pragma unroll
        for (int j = 0; j < 4; ++j) {
            const float e2 = __expf(2.f * acc[i][j]);
            acc[i][j] = 1.f - 2.f / (e2 + 1.f);
        }

    if (!final_mode) {
        #pragma unroll
        for (int i = 0; i < 4; ++i) {
            const int node = n0 + nb + i;
            if (node < N) {
                *reinterpret_cast<float4*>(&x1f[(size_t)node * 64 + og * 4]) =
                    make_float4(acc[i][0], acc[i][1], acc[i][2], acc[i][3]);
                const unsigned long long pk =
                    (unsigned long long)f2b(acc[i][0]) |
                    ((unsigned long long)f2b(acc[i][1]) << 16) |
                    ((unsigned long long)f2b(acc[i][2]) << 32) |
                    ((unsigned long long)f2b(acc[i][3]) << 48);
                *reinterpret_cast<unsigned long long*>(&out16[(size_t)node * 64 + og * 4]) = pk;
            }
        }
    } else {
        float* TL = reinterpret_cast<float*>(fav);   // reuse A buffer, [64][65]
        __syncthreads();                              // all A reads done
        #pragma unroll
        for (int i = 0; i < 4; ++i)
            #pragma unroll
            for (int j = 0; j < 4; ++j)
                TL[(nb + i) * 65 + og * 4 + j] = acc[i][j];
        __syncthreads();
        const int l = tid & 63, cg = (tid >> 6) * 4;
        float o0 = bp[cg], o1 = bp[cg + 1], o2 = bp[cg + 2], o3 = bp[cg + 3];
        for (int d = 0; d < 64; ++d) {
            const float tv = TL[l * 65 + d];
            const float4 wp = *reinterpret_cast<const float4*>(&Wp[d * 16 + cg]);
            o0 += tv * wp.x; o1 += tv * wp.y; o2 += tv * wp.z; o3 += tv * wp.w;
        }
        const int node = n0 + l;
        if (node < N)
            *reinterpret_cast<float4*>(&outf[(size_t)node * 16 + cg]) =
                make_float4(o0, o1, o2, o3);
    }
}

extern "C" void kernel_launch(void* const* d_in, const int* in_sizes, int n_in,
                              void* d_out, int out_size, void* d_ws, size_t ws_size,
                              hipStream_t stream)
{
    const float* cl_h   = (const float*)d_in[0];
    const float* cl_w   = (const float*)d_in[1];
    const int*   cl_src = (const int*)d_in[2];
    const int*   cl_dst = (const int*)d_in[3];
    const int*   g_src  = (const int*)d_in[4];
    const int*   g_dst  = (const int*)d_in[5];
    const int*   g_et   = (const int*)d_in[6];
    const float* feats  = (const float*)d_in[7];
    const float* W_e    = (const float*)d_in[8];
    const float* b1     = (const float*)d_in[9];
    const float* e1     = (const float*)d_in[10];
    const float* b2     = (const float*)d_in[11];
    const float* e2     = (const float*)d_in[12];
    const float* W1a    = (const float*)d_in[13];
    const float* W2a    = (const float*)d_in[14];
    const float* W1b    = (const float*)d_in[15];
    const float* W2b    = (const float*)d_in[16];
    const float* Wp     = (const float*)d_in[17];
    const float* bp     = (const float*)d_in[18];
    const int ECL = in_sizes[1];
    const int E   = in_sizes[4];
    const int N   = in_sizes[7] / 64;
    const int NB  = (N + 255) >> 8;

    char* w = (char*)d_ws;
    auto carve = [&](size_t bytes) {
        char* r = w;
        w += (bytes + 255) & ~(size_t)255;
        return r;
    };
    float*          hW    = (float*)carve(32 * 64 * sizeof(float));
    int*            off   = (int*)carve((size_t)(N + 1) * sizeof(int));
    int*            bcnt  = (int*)carve(256 * sizeof(int));
    int*            bbase = (int*)carve(257 * sizeof(int));
    int*            bcur  = (int*)carve(256 * sizeof(int));
    unsigned*       etmp  = (unsigned*)carve((size_t)E * sizeof(unsigned));
    unsigned*       ssrc  = (unsigned*)carve((size_t)E * sizeof(unsigned));
    unsigned short* fb16  = (unsigned short*)carve((size_t)N * 64 * sizeof(unsigned short));
    unsigned short* x16   = (unsigned short*)carve((size_t)N * 64 * sizeof(unsigned short));
    float*          aggF  = (float*)carve((size_t)N * 64 * sizeof(float));
    float*          x1f   = (float*)carve((size_t)N * 64 * sizeof(float));

    const int nblk = (E + TILE - 1) / TILE;
    const int total8 = N * 8;
    const int nng = (N + 3) / 4;                 // node groups (4 nodes each)
    const int spmm_grid = ((nng + 3) / 4) * 8;   // x2 column halves, XCD-keyed

    agnn_kernel<<<1, 512, 0, stream>>>(cl_h, cl_w, cl_src, cl_dst, W_e,
                                       b1, e1, b2, e2, hW, bcnt, ECL);
    tobf16_kernel<<<(total8 + 255) / 256, 256, 0, stream>>>(feats, fb16, total8);
    bucket_count<<<nblk, 256, 0, stream>>>(g_dst, bcnt, E);
    bucket_scan<<<1, 256, 0, stream>>>(bcnt, bbase, bcur);
    bucket_scatter<<<nblk, 256, 0, stream>>>(g_src, g_dst, g_et, bcur, etmp, E);
    csr_kernel<<<NB, 256, 0, stream>>>(etmp, bbase, off, ssrc, N, NB);
    spmm_kernel<<<spmm_grid, 256, 0, stream>>>(fb16, hW, off, ssrc, aggF, N);
    gconv_kernel<<<(N + 63) / 64, 256, 0, stream>>>(feats, aggF, W1a, W2a,
                                                    x1f, x16, nullptr, N, 0, Wp, bp);
    spmm_kernel<<<spmm_grid, 256, 0, stream>>>(x16, hW, off, ssrc, aggF, N);
    gconv_kernel<<<(N + 63) / 64, 256, 0, stream>>>(x1f, aggF, W1b, W2b,
                                                    nullptr, nullptr, (float*)d_out, N, 1, Wp, bp);
}

// Round 18
// 220.908 us; speedup vs baseline: 1.2433x; 1.2433x over previous
//
#include <hip/hip_runtime.h>

// ---------------------------------------------------------------------------
// FINAL (round-11 empirical best, 221 us):
//  1. agnn_kernel (1 block): 2x AGNN on line graph -> hW = h @ W_e [32,64];
//     zeroes bcnt in-kernel
//  2. tobf16: feats fp32 -> fb16 (bf16 rows for the random gather only)
//  3. bucket_count/scan/scatter + csr: 2-level counting sort -> CSR (off, ssrc)
//  4. spmm: aggF[n] = sum_in (gather_bf16[src] - hW[et]); 8 gathers in flight
//     per half-wave; fp32 accum + out
//  5. gconv: register-tiled GEMM K=128 (thread = 4 nodes x 4 outs, A+W in LDS,
//     8 FMA per ds_read_b128); final layer fuses pred head via TL reuse.
// ---------------------------------------------------------------------------

#define TILE 8192

typedef __attribute__((ext_vector_type(8))) unsigned short us8;

__device__ __forceinline__ float b2f(unsigned short h) {
    return __uint_as_float(((unsigned)h) << 16);
}
__device__ __forceinline__ unsigned short f2b(float f) {
    const unsigned u = __float_as_uint(f);
    return (unsigned short)((u + 0x7FFFu + ((u >> 16) & 1u)) >> 16);
}

__device__ __forceinline__ unsigned ford_enc(float v) {
    unsigned b = __float_as_uint(v);
    return (b & 0x80000000u) ? ~b : (b | 0x80000000u);
}
__device__ __forceinline__ float ford_dec(unsigned k) {
    return __uint_as_float((k & 0x80000000u) ? (k ^ 0x80000000u) : ~k);
}

__global__ __launch_bounds__(512) void agnn_kernel(
    const float* __restrict__ cl_h, const float* __restrict__ cl_w,
    const int* __restrict__ cl_src, const int* __restrict__ cl_dst,
    const float* __restrict__ W_e,
    const float* __restrict__ pb1, const float* __restrict__ pe1,
    const float* __restrict__ pb2, const float* __restrict__ pe2,
    float* __restrict__ hW, int* __restrict__ bcnt, int ECL)
{
    __shared__ float w_s[1024];
    __shared__ int   src_s[1024];
    __shared__ int   dst_s[1024];
    __shared__ float h[32][16];
    __shared__ float nh[32][16];
    __shared__ float p[1024];
    __shared__ float red[32][16];
    __shared__ float acc16[32][16][16];
    __shared__ unsigned mI[32];
    __shared__ float m[32], ssum[32], nrm[32];
    const int tid = threadIdx.x;
    const int seg = tid >> 4, j = tid & 15;

    if (tid < 256) bcnt[tid] = 0;

    for (int e = tid; e < ECL; e += 512) {
        w_s[e] = cl_w[e]; src_s[e] = cl_src[e]; dst_s[e] = cl_dst[e];
    }
    h[tid >> 4][tid & 15] = cl_h[tid];
    __syncthreads();

    for (int layer = 0; layer < 2; ++layer) {
        const float beta = layer ? *pb2 : *pb1;
        const float eps  = layer ? *pe2 : *pe1;

        if (tid < 32) mI[tid] = ford_enc(-3.4e38f);
        __syncthreads();
        for (int e = tid; e < ECL; e += 512)
            atomicMax(&mI[src_s[e]], ford_enc(beta * w_s[e]));
        __syncthreads();
        if (tid < 32) m[tid] = ford_dec(mI[tid]);
        __syncthreads();

        for (int e = tid; e < ECL; e += 512)
            p[e] = __expf(beta * w_s[e] - m[src_s[e]]);
        __syncthreads();

        {
            float s = 0.f;
            #pragma unroll 4
            for (int e = j; e < ECL; e += 16)
                s += (src_s[e] == seg) ? p[e] : 0.f;
            red[seg][j] = s;
        }
        __syncthreads();
        if (tid < 32) {
            float s = 0.f;
            #pragma unroll
            for (int k = 0; k < 16; ++k) s += red[tid][k];
            ssum[tid] = s;
            float q = 0.f;
            #pragma unroll
            for (int f = 0; f < 16; ++f) { float v = h[tid][f]; q += v * v; }
            nrm[tid] = fmaxf(sqrtf(q), 1e-12f);
        }
        __syncthreads();
        for (int e = tid; e < ECL; e += 512)
            p[e] = p[e] / ssum[src_s[e]];
        nh[tid >> 4][tid & 15] = h[tid >> 4][tid & 15] / nrm[tid >> 4];
        __syncthreads();

        {
            float facc[16];
            #pragma unroll
            for (int f = 0; f < 16; ++f) facc[f] = 0.f;
            #pragma unroll 4
            for (int e = j; e < ECL; e += 16) {
                if (dst_s[e] == seg) {
                    const float pe = p[e];
                    const float4* nhrow = reinterpret_cast<const float4*>(&nh[src_s[e]][0]);
                    const float4 a0 = nhrow[0], a1 = nhrow[1], a2 = nhrow[2], a3 = nhrow[3];
                    facc[0] += pe * a0.x; facc[1] += pe * a0.y; facc[2] += pe * a0.z; facc[3] += pe * a0.w;
                    facc[4] += pe * a1.x; facc[5] += pe * a1.y; facc[6] += pe * a1.z; facc[7] += pe * a1.w;
                    facc[8] += pe * a2.x; facc[9] += pe * a2.y; facc[10] += pe * a2.z; facc[11] += pe * a2.w;
                    facc[12] += pe * a3.x; facc[13] += pe * a3.y; facc[14] += pe * a3.z; facc[15] += pe * a3.w;
                }
            }
            #pragma unroll
            for (int f = 0; f < 16; ++f) acc16[seg][j][f] = facc[f];
        }
        __syncthreads();
        {
            const int t = tid >> 4, f = tid & 15;
            float a = 0.f;
            #pragma unroll
            for (int k = 0; k < 16; ++k) a += acc16[t][k][f];
            float v = (1.f + eps) * h[t][f] + a;
            h[t][f] = fmaxf(v, 0.f);
        }
        __syncthreads();
    }

    for (int o = tid; o < 2048; o += 512) {
        const int t = o >> 6, d = o & 63;
        float s = 0.f;
        #pragma unroll
        for (int f = 0; f < 16; ++f) s += h[t][f] * W_e[f * 64 + d];
        hW[o] = s;
    }
}

__global__ __launch_bounds__(256) void tobf16_kernel(
    const float* __restrict__ x, unsigned short* __restrict__ y, int total8)
{
    const int i = blockIdx.x * 256 + threadIdx.x;
    if (i >= total8) return;
    const int base = i * 8;
    const float4 a = *reinterpret_cast<const float4*>(&x[base]);
    const float4 b = *reinterpret_cast<const float4*>(&x[base + 4]);
    us8 o;
    o[0] = f2b(a.x); o[1] = f2b(a.y); o[2] = f2b(a.z); o[3] = f2b(a.w);
    o[4] = f2b(b.x); o[5] = f2b(b.y); o[6] = f2b(b.z); o[7] = f2b(b.w);
    *reinterpret_cast<us8*>(&y[base]) = o;
}

__global__ __launch_bounds__(256) void bucket_count(
    const int* __restrict__ dst, int* __restrict__ bcnt, int E)
{
    __shared__ int lh[256];
    const int tid = threadIdx.x;
    lh[tid] = 0;
    __syncthreads();
    const int base = blockIdx.x * TILE;
    #pragma unroll
    for (int it = 0; it < 8; ++it) {
        const int i = base + (it * 256 + tid) * 4;
        if (i + 3 < E) {
            const int4 d = *reinterpret_cast<const int4*>(&dst[i]);
            atomicAdd(&lh[d.x >> 8], 1); atomicAdd(&lh[d.y >> 8], 1);
            atomicAdd(&lh[d.z >> 8], 1); atomicAdd(&lh[d.w >> 8], 1);
        } else {
            for (int k = i; k < E && k < i + 4; ++k) atomicAdd(&lh[dst[k] >> 8], 1);
        }
    }
    __syncthreads();
    if (lh[tid]) atomicAdd(&bcnt[tid], lh[tid]);
}

__global__ __launch_bounds__(256) void bucket_scan(
    const int* __restrict__ bcnt, int* __restrict__ bbase, int* __restrict__ bcur)
{
    __shared__ int ws[4];
    const int tid = threadIdx.x, lane = tid & 63, wv = tid >> 6;
    const int v = bcnt[tid];
    int x = v;
    #pragma unroll
    for (int s = 1; s < 64; s <<= 1) { const int t = __shfl_up(x, s, 64); if (lane >= s) x += t; }
    if (lane == 63) ws[wv] = x;
    __syncthreads();
    if (tid == 0) { int a = ws[0]; ws[0] = 0; for (int k = 1; k < 4; ++k) { const int b = ws[k]; ws[k] = a; a += b; } }
    __syncthreads();
    const int excl = ws[wv] + x - v;
    bbase[tid] = excl; bcur[tid] = excl;
    if (tid == 255) bbase[256] = excl + v;
}

__global__ __launch_bounds__(256) void bucket_scatter(
    const int* __restrict__ src, const int* __restrict__ dst, const int* __restrict__ et,
    int* __restrict__ bcur, unsigned* __restrict__ etmp, int E)
{
    __shared__ int lh[256], lofs[256], lcur[256], gbase[256];
    __shared__ int ws[4];
    __shared__ unsigned stage[TILE];
    __shared__ unsigned char sbk[TILE];
    const int tid = threadIdx.x, lane = tid & 63, wv = tid >> 6;
    lh[tid] = 0;
    __syncthreads();
    const int base = blockIdx.x * TILE;
    #pragma unroll
    for (int it = 0; it < 8; ++it) {
        const int i = base + (it * 256 + tid) * 4;
        if (i + 3 < E) {
            const int4 d = *reinterpret_cast<const int4*>(&dst[i]);
            atomicAdd(&lh[d.x >> 8], 1); atomicAdd(&lh[d.y >> 8], 1);
            atomicAdd(&lh[d.z >> 8], 1); atomicAdd(&lh[d.w >> 8], 1);
        } else {
            for (int k = i; k < E && k < i + 4; ++k) atomicAdd(&lh[dst[k] >> 8], 1);
        }
    }
    __syncthreads();
    {
        const int v = lh[tid];
        int x = v;
        #pragma unroll
        for (int s = 1; s < 64; s <<= 1) { const int t = __shfl_up(x, s, 64); if (lane >= s) x += t; }
        if (lane == 63) ws[wv] = x;
        __syncthreads();
        if (tid == 0) { int a = ws[0]; ws[0] = 0; for (int k = 1; k < 4; ++k) { const int b = ws[k]; ws[k] = a; a += b; } }
        __syncthreads();
        const int excl = ws[wv] + x - v;
        lofs[tid] = excl; lcur[tid] = excl;
        if (v) gbase[tid] = atomicAdd(&bcur[tid], v);
    }
    __syncthreads();
    #pragma unroll
    for (int it = 0; it < 8; ++it) {
        const int i = base + (it * 256 + tid) * 4;
        if (i + 3 < E) {
            const int4 d  = *reinterpret_cast<const int4*>(&dst[i]);
            const int4 s4 = *reinterpret_cast<const int4*>(&src[i]);
            const int4 t4 = *reinterpret_cast<const int4*>(&et[i]);
            int b, r;
            b = d.x >> 8; r = atomicAdd(&lcur[b], 1);
            stage[r] = (unsigned)s4.x | ((unsigned)(d.x & 255) << 16) | ((unsigned)t4.x << 24); sbk[r] = (unsigned char)b;
            b = d.y >> 8; r = atomicAdd(&lcur[b], 1);
            stage[r] = (unsigned)s4.y | ((unsigned)(d.y & 255) << 16) | ((unsigned)t4.y << 24); sbk[r] = (unsigned char)b;
            b = d.z >> 8; r = atomicAdd(&lcur[b], 1);
            stage[r] = (unsigned)s4.z | ((unsigned)(d.z & 255) << 16) | ((unsigned)t4.z << 24); sbk[r] = (unsigned char)b;
            b = d.w >> 8; r = atomicAdd(&lcur[b], 1);
            stage[r] = (unsigned)s4.w | ((unsigned)(d.w & 255) << 16) | ((unsigned)t4.w << 24); sbk[r] = (unsigned char)b;
        } else {
            for (int k = i; k < E && k < i + 4; ++k) {
                const int b = dst[k] >> 8;
                const int r = atomicAdd(&lcur[b], 1);
                stage[r] = (unsigned)src[k] | ((unsigned)(dst[k] & 255) << 16) | ((unsigned)et[k] << 24);
                sbk[r] = (unsigned char)b;
            }
        }
    }
    __syncthreads();
    const int tot = lofs[255] + lh[255];
    for (int i = tid; i < tot; i += 256) {
        const int b = sbk[i];
        etmp[gbase[b] + (i - lofs[b])] = stage[i];
    }
}

__global__ __launch_bounds__(256) void csr_kernel(
    const unsigned* __restrict__ etmp, const int* __restrict__ bbase,
    int* __restrict__ off, unsigned* __restrict__ ssrc, int N, int NB)
{
    __shared__ int lh[256], lofs[256], lcur[256];
    __shared__ int ws[4];
    const int tid = threadIdx.x, lane = tid & 63, wv = tid >> 6;
    const int b = blockIdx.x;
    const int s = bbase[b], e = bbase[b + 1];
    lh[tid] = 0;
    __syncthreads();
    for (int i = s + tid; i < e; i += 256)
        atomicAdd(&lh[(etmp[i] >> 16) & 255], 1);
    __syncthreads();
    {
        const int v = lh[tid];
        int x = v;
        #pragma unroll
        for (int ss = 1; ss < 64; ss <<= 1) { const int t = __shfl_up(x, ss, 64); if (lane >= ss) x += t; }
        if (lane == 63) ws[wv] = x;
        __syncthreads();
        if (tid == 0) { int a = ws[0]; ws[0] = 0; for (int k = 1; k < 4; ++k) { const int c = ws[k]; ws[k] = a; a += c; } }
        __syncthreads();
        const int excl = ws[wv] + x - v;
        lofs[tid] = excl; lcur[tid] = excl;
    }
    __syncthreads();
    const int n0 = b << 8;
    if (n0 + tid < N) off[n0 + tid] = s + lofs[tid];
    if (b == NB - 1 && tid == 0) off[N] = e;
    for (int i = s + tid; i < e; i += 256) {
        const unsigned pp = etmp[i];
        const int dl = (pp >> 16) & 255;
        const int r = atomicAdd(&lcur[dl], 1);
        ssrc[s + r] = pp;
    }
}

// aggF[n] = sum over incoming edges (bf16 gather[src] - hW[et]); fp32 accum.
// 8 row-gathers in flight per half-wave to cover L2-miss/L3 latency.
__global__ __launch_bounds__(256) void spmm_kernel(
    const unsigned short* __restrict__ fb, const float* __restrict__ hW,
    const int* __restrict__ off, const unsigned* __restrict__ ssrc,
    float* __restrict__ aggF, int N)
{
    __shared__ float hWl[2048];
    for (int i = threadIdx.x; i < 2048; i += 256) hWl[i] = hW[i];
    __syncthreads();
    const int lane = threadIdx.x & 63;
    const int n = blockIdx.x * 4 + (threadIdx.x >> 6);
    if (n >= N) return;
    const int half = lane >> 5, c = lane & 31;
    const int beg = off[n], end = off[n + 1];
    float a0 = 0.f, a1 = 0.f;
    int i = beg + half;
    for (; i + 14 < end; i += 16) {
        unsigned pp[8];
        #pragma unroll
        for (int jj = 0; jj < 8; ++jj) pp[jj] = ssrc[i + 2 * jj];
        unsigned u[8];
        #pragma unroll
        for (int jj = 0; jj < 8; ++jj)
            u[jj] = *reinterpret_cast<const unsigned*>(
                &fb[(size_t)(pp[jj] & 0xFFFFu) * 64 + 2 * c]);
        #pragma unroll
        for (int jj = 0; jj < 8; ++jj) {
            const float2 hw = *reinterpret_cast<const float2*>(
                &hWl[(pp[jj] >> 24) * 64 + 2 * c]);
            a0 += b2f((unsigned short)(u[jj] & 0xFFFFu)) - hw.x;
            a1 += b2f((unsigned short)(u[jj] >> 16)) - hw.y;
        }
    }
    for (; i + 6 < end; i += 8) {
        unsigned pp[4];
        #pragma unroll
        for (int jj = 0; jj < 4; ++jj) pp[jj] = ssrc[i + 2 * jj];
        unsigned u[4];
        #pragma unroll
        for (int jj = 0; jj < 4; ++jj)
            u[jj] = *reinterpret_cast<const unsigned*>(
                &fb[(size_t)(pp[jj] & 0xFFFFu) * 64 + 2 * c]);
        #pragma unroll
        for (int jj = 0; jj < 4; ++jj) {
            const float2 hw = *reinterpret_cast<const float2*>(
                &hWl[(pp[jj] >> 24) * 64 + 2 * c]);
            a0 += b2f((unsigned short)(u[jj] & 0xFFFFu)) - hw.x;
            a1 += b2f((unsigned short)(u[jj] >> 16)) - hw.y;
        }
    }
    for (; i < end; i += 2) {
        const unsigned pp = ssrc[i];
        const unsigned u = *reinterpret_cast<const unsigned*>(
            &fb[(size_t)(pp & 0xFFFFu) * 64 + 2 * c]);
        const float2 hw = *reinterpret_cast<const float2*>(
            &hWl[(pp >> 24) * 64 + 2 * c]);
        a0 += b2f((unsigned short)(u & 0xFFFFu)) - hw.x;
        a1 += b2f((unsigned short)(u >> 16)) - hw.y;
    }
    a0 += __shfl_xor(a0, 32);
    a1 += __shfl_xor(a1, 32);
    if (half == 0)
        *reinterpret_cast<float2*>(&aggF[(size_t)n * 64 + 2 * c]) = make_float2(a0, a1);
}

// Register-tiled GEMM: thread (ng=tid&15, og=tid>>4) computes 4 nodes x 4 outs.
// Per k-chunk(4): 4 A-float4 (swizzled) + 4 W-float4 -> 64 FMAs / 8 ds_reads.
__global__ __launch_bounds__(256) void gconv_kernel(
    const float* __restrict__ Xf, const float* __restrict__ Af,
    const float* __restrict__ W1, const float* __restrict__ W2,
    float* __restrict__ x1f, unsigned short* __restrict__ out16,
    float* __restrict__ outf, int N, int final_mode,
    const float* __restrict__ Wp, const float* __restrict__ bp)
{
    __shared__ float4 fav[64 * 32];   // A/X, 32 KB, chunk ^= (row>>2)&7 swizzle
    __shared__ float4 Wl[128 * 16];   // W rows, 32 KB
    const int tid = threadIdx.x;
    const int ng = tid & 15, og = tid >> 4;
    const int n0 = blockIdx.x * 64;
    const int nb = ng * 4;

    #pragma unroll
    for (int q = 0; q < 8; ++q) {
        const int idx = q * 256 + tid;     // 0..2047
        Wl[idx] = (idx < 1024)
            ? reinterpret_cast<const float4*>(W1)[idx]
            : reinterpret_cast<const float4*>(W2)[idx - 1024];
    }
    #pragma unroll
    for (int q = 0; q < 8; ++q) {
        const int cch = q * 256 + tid;     // 0..2047
        const int row = cch >> 5, p = cch & 31;
        const int rn = n0 + row;
        float4 v = make_float4(0.f, 0.f, 0.f, 0.f);
        if (rn < N)
            v = (p < 16) ? reinterpret_cast<const float4*>(Xf)[(size_t)rn * 16 + p]
                         : reinterpret_cast<const float4*>(Af)[(size_t)rn * 16 + (p - 16)];
        fav[row * 32 + (p ^ ((row >> 2) & 7))] = v;
    }
    __syncthreads();

    float acc[4][4];
    #pragma unroll
    for (int i = 0; i < 4; ++i)
        #pragma unroll
        for (int j = 0; j < 4; ++j) acc[i][j] = 0.f;

    const int swz = ng & 7;
    #pragma unroll 2
    for (int kc = 0; kc < 32; ++kc) {
        const int pc = kc ^ swz;
        const float4 a0 = fav[(nb + 0) * 32 + pc];
        const float4 a1 = fav[(nb + 1) * 32 + pc];
        const float4 a2 = fav[(nb + 2) * 32 + pc];
        const float4 a3 = fav[(nb + 3) * 32 + pc];
        const float4 w0 = Wl[(kc * 4 + 0) * 16 + og];
        const float4 w1 = Wl[(kc * 4 + 1) * 16 + og];
        const float4 w2 = Wl[(kc * 4 + 2) * 16 + og];
        const float4 w3 = Wl[(kc * 4 + 3) * 16 + og];
        #pragma unroll
        for (int i = 0; i < 4; ++i) {
            const float4 a = (i == 0) ? a0 : (i == 1) ? a1 : (i == 2) ? a2 : a3;
            acc[i][0] += a.x * w0.x + a.y * w1.x + a.z * w2.x + a.w * w3.x;
            acc[i][1] += a.x * w0.y + a.y * w1.y + a.z * w2.y + a.w * w3.y;
            acc[i][2] += a.x * w0.z + a.y * w1.z + a.z * w2.z + a.w * w3.z;
            acc[i][3] += a.x * w0.w + a.y * w1.w + a.z * w2.w + a.w * w3.w;
        }
    }

    #pragma unroll
    for (int i = 0; i < 4; ++i)
        #pragma unroll
        for (int j = 0; j < 4; ++j) {
            const float e2 = __expf(2.f * acc[i][j]);
            acc[i][j] = 1.f - 2.f / (e2 + 1.f);
        }

    if (!final_mode) {
        #pragma unroll
        for (int i = 0; i < 4; ++i) {
            const int node = n0 + nb + i;
            if (node < N) {
                *reinterpret_cast<float4*>(&x1f[(size_t)node * 64 + og * 4]) =
                    make_float4(acc[i][0], acc[i][1], acc[i][2], acc[i][3]);
                const unsigned long long pk =
                    (unsigned long long)f2b(acc[i][0]) |
                    ((unsigned long long)f2b(acc[i][1]) << 16) |
                    ((unsigned long long)f2b(acc[i][2]) << 32) |
                    ((unsigned long long)f2b(acc[i][3]) << 48);
                *reinterpret_cast<unsigned long long*>(&out16[(size_t)node * 64 + og * 4]) = pk;
            }
        }
    } else {
        float* TL = reinterpret_cast<float*>(fav);   // reuse A buffer, [64][65]
        __syncthreads();                              // all A reads done
        #pragma unroll
        for (int i = 0; i < 4; ++i)
            #pragma unroll
            for (int j = 0; j < 4; ++j)
                TL[(nb + i) * 65 + og * 4 + j] = acc[i][j];
        __syncthreads();
        const int l = tid & 63, cg = (tid >> 6) * 4;
        float o0 = bp[cg], o1 = bp[cg + 1], o2 = bp[cg + 2], o3 = bp[cg + 3];
        for (int d = 0; d < 64; ++d) {
            const float tv = TL[l * 65 + d];
            const float4 wp = *reinterpret_cast<const float4*>(&Wp[d * 16 + cg]);
            o0 += tv * wp.x; o1 += tv * wp.y; o2 += tv * wp.z; o3 += tv * wp.w;
        }
        const int node = n0 + l;
        if (node < N)
            *reinterpret_cast<float4*>(&outf[(size_t)node * 16 + cg]) =
                make_float4(o0, o1, o2, o3);
    }
}

extern "C" void kernel_launch(void* const* d_in, const int* in_sizes, int n_in,
                              void* d_out, int out_size, void* d_ws, size_t ws_size,
                              hipStream_t stream)
{
    const float* cl_h   = (const float*)d_in[0];
    const float* cl_w   = (const float*)d_in[1];
    const int*   cl_src = (const int*)d_in[2];
    const int*   cl_dst = (const int*)d_in[3];
    const int*   g_src  = (const int*)d_in[4];
    const int*   g_dst  = (const int*)d_in[5];
    const int*   g_et   = (const int*)d_in[6];
    const float* feats  = (const float*)d_in[7];
    const float* W_e    = (const float*)d_in[8];
    const float* b1     = (const float*)d_in[9];
    const float* e1     = (const float*)d_in[10];
    const float* b2     = (const float*)d_in[11];
    const float* e2     = (const float*)d_in[12];
    const float* W1a    = (const float*)d_in[13];
    const float* W2a    = (const float*)d_in[14];
    const float* W1b    = (const float*)d_in[15];
    const float* W2b    = (const float*)d_in[16];
    const float* Wp     = (const float*)d_in[17];
    const float* bp     = (const float*)d_in[18];
    const int ECL = in_sizes[1];
    const int E   = in_sizes[4];
    const int N   = in_sizes[7] / 64;
    const int NB  = (N + 255) >> 8;

    char* w = (char*)d_ws;
    auto carve = [&](size_t bytes) {
        char* r = w;
        w += (bytes + 255) & ~(size_t)255;
        return r;
    };
    float*          hW    = (float*)carve(32 * 64 * sizeof(float));
    int*            off   = (int*)carve((size_t)(N + 1) * sizeof(int));
    int*            bcnt  = (int*)carve(256 * sizeof(int));
    int*            bbase = (int*)carve(257 * sizeof(int));
    int*            bcur  = (int*)carve(256 * sizeof(int));
    unsigned*       etmp  = (unsigned*)carve((size_t)E * sizeof(unsigned));
    unsigned*       ssrc  = (unsigned*)carve((size_t)E * sizeof(unsigned));
    unsigned short* fb16  = (unsigned short*)carve((size_t)N * 64 * sizeof(unsigned short));
    unsigned short* x16   = (unsigned short*)carve((size_t)N * 64 * sizeof(unsigned short));
    float*          aggF  = (float*)carve((size_t)N * 64 * sizeof(float));
    float*          x1f   = (float*)carve((size_t)N * 64 * sizeof(float));

    const int nblk = (E + TILE - 1) / TILE;
    const int total8 = N * 8;

    agnn_kernel<<<1, 512, 0, stream>>>(cl_h, cl_w, cl_src, cl_dst, W_e,
                                       b1, e1, b2, e2, hW, bcnt, ECL);
    tobf16_kernel<<<(total8 + 255) / 256, 256, 0, stream>>>(feats, fb16, total8);
    bucket_count<<<nblk, 256, 0, stream>>>(g_dst, bcnt, E);
    bucket_scan<<<1, 256, 0, stream>>>(bcnt, bbase, bcur);
    bucket_scatter<<<nblk, 256, 0, stream>>>(g_src, g_dst, g_et, bcur, etmp, E);
    csr_kernel<<<NB, 256, 0, stream>>>(etmp, bbase, off, ssrc, N, NB);
    spmm_kernel<<<(N + 3) / 4, 256, 0, stream>>>(fb16, hW, off, ssrc, aggF, N);
    gconv_kernel<<<(N + 63) / 64, 256, 0, stream>>>(feats, aggF, W1a, W2a,
                                                    x1f, x16, nullptr, N, 0, Wp, bp);
    spmm_kernel<<<(N + 3) / 4, 256, 0, stream>>>(x16, hW, off, ssrc, aggF, N);
    gconv_kernel<<<(N + 63) / 64, 256, 0, stream>>>(x1f, aggF, W1b, W2b,
                                                    nullptr, nullptr, (float*)d_out, N, 1, Wp, bp);
}